// Round 1
// baseline (103.459 us; speedup 1.0000x reference)
//
#include <hip/hip_runtime.h>
#include <math.h>

#define PI_F 3.14159265358979323846f

constexpr int IMG_H = 1024;
constexpr int IMG_W = 2048;
constexpr int BLOCK = 256;
constexpr int GRID  = 2048;

// Stage 1: fused transform + projection + bilinear sample + masked loss,
// per-block deterministic reduction into double partials.
__global__ __launch_bounds__(BLOCK) void sampling_loss_partial(
    const float* __restrict__ translation,  // (3,)
    const float* __restrict__ yaw,          // (1,)
    const float* __restrict__ pitch,        // (1,)
    const float* __restrict__ roll,         // (1,)
    const float* __restrict__ xyz,          // (N,3)
    const float* __restrict__ rgb,          // (N,3)
    const float* __restrict__ img,          // (H,W,3)
    const float* __restrict__ imgw,         // (H,W,1)
    const float* __restrict__ pcdw,         // (N,)
    double* __restrict__ partials,          // (GRID,2)
    int N)
{
    // Rotation matrix R = RZ @ RY @ RX (computed once per thread; scalar loads hit L2)
    const float cyw = cosf(yaw[0]),   syw = sinf(yaw[0]);
    const float cpw = cosf(pitch[0]), spw = sinf(pitch[0]);
    const float crw = cosf(roll[0]),  srw = sinf(roll[0]);

    const float R00 = cyw * cpw;
    const float R01 = -syw * crw + cyw * spw * srw;
    const float R02 =  syw * srw + cyw * spw * crw;
    const float R10 =  syw * cpw;
    const float R11 =  cyw * crw + syw * spw * srw;
    const float R12 = -cyw * srw + syw * spw * crw;
    const float R20 = -spw;
    const float R21 =  cpw * srw;
    const float R22 =  cpw * crw;

    const float tx = translation[0], ty = translation[1], tz = translation[2];

    double acc_loss = 0.0;
    double acc_mask = 0.0;

    for (int i = blockIdx.x * BLOCK + threadIdx.x; i < N; i += GRID * BLOCK) {
        const float px = xyz[3 * i + 0] - tx;
        const float py = xyz[3 * i + 1] - ty;
        const float pz = xyz[3 * i + 2] - tz;

        const float nx = R00 * px + R01 * py + R02 * pz;
        const float ny = R10 * px + R11 * py + R12 * pz;
        const float nz = R20 * px + R21 * py + R22 * pz;

        // spherical projection -> [-1,1] panorama coords
        const float phi   = atan2f(ny, nx) + PI_F;                 // [0, 2pi]
        const float theta = atan2f(sqrtf(nx * nx + ny * ny), nz);  // [0, pi]
        const float cx = 2.0f * (1.0f - phi / (2.0f * PI_F)) - 1.0f;
        const float cyv = 2.0f * (theta / PI_F) - 1.0f;

        // grid_sample coords, align_corners=False, border clamp
        float fx = (cx + 1.0f) * 0.5f * (float)IMG_W - 0.5f;
        float fy = (cyv + 1.0f) * 0.5f * (float)IMG_H - 0.5f;
        fx = fminf(fmaxf(fx, 0.0f), (float)(IMG_W - 1));
        fy = fminf(fmaxf(fy, 0.0f), (float)(IMG_H - 1));

        const float x0f = floorf(fx), y0f = floorf(fy);
        const float wx = fx - x0f,    wy = fy - y0f;
        const int x0 = (int)x0f, y0 = (int)y0f;
        const int x1 = min(x0 + 1, IMG_W - 1);
        const int y1 = min(y0 + 1, IMG_H - 1);

        const float w00 = (1.0f - wx) * (1.0f - wy);
        const float w01 = wx * (1.0f - wy);
        const float w10 = (1.0f - wx) * wy;
        const float w11 = wx * wy;

        const float* p00 = img + (size_t)(y0 * IMG_W + x0) * 3;
        const float* p01 = img + (size_t)(y0 * IMG_W + x1) * 3;
        const float* p10 = img + (size_t)(y1 * IMG_W + x0) * 3;
        const float* p11 = img + (size_t)(y1 * IMG_W + x1) * 3;

        const float s0 = w00 * p00[0] + w01 * p01[0] + w10 * p10[0] + w11 * p11[0];
        const float s1 = w00 * p00[1] + w01 * p01[1] + w10 * p10[1] + w11 * p11[1];
        const float s2 = w00 * p00[2] + w01 * p01[2] + w10 * p10[2] + w11 * p11[2];

        const float wimg = w00 * imgw[y0 * IMG_W + x0] + w01 * imgw[y0 * IMG_W + x1]
                         + w10 * imgw[y1 * IMG_W + x0] + w11 * imgw[y1 * IMG_W + x1];

        const float dr = s0 - rgb[3 * i + 0];
        const float dg = s1 - rgb[3 * i + 1];
        const float db = s2 - rgb[3 * i + 2];
        const float raw = sqrtf(dr * dr + dg * dg + db * db);

        const bool mask = !((s0 == 0.0f) && (s1 == 0.0f) && (s2 == 0.0f));

        const float li = 0.5f * (wimg + pcdw[i]) * raw;
        if (mask) {
            acc_loss += (double)li;
            acc_mask += 1.0;
        }
    }

    // wave64 shuffle reduction (deterministic tree)
    for (int off = 32; off > 0; off >>= 1) {
        acc_loss += __shfl_down(acc_loss, off);
        acc_mask += __shfl_down(acc_mask, off);
    }

    __shared__ double sL[BLOCK / 64];
    __shared__ double sM[BLOCK / 64];
    const int lane = threadIdx.x & 63;
    const int wave = threadIdx.x >> 6;
    if (lane == 0) { sL[wave] = acc_loss; sM[wave] = acc_mask; }
    __syncthreads();
    if (threadIdx.x == 0) {
        double L = 0.0, M = 0.0;
        for (int w = 0; w < BLOCK / 64; ++w) { L += sL[w]; M += sM[w]; }
        partials[2 * blockIdx.x + 0] = L;
        partials[2 * blockIdx.x + 1] = M;
    }
}

// Stage 2: single-block deterministic reduction of partials -> scalar out.
__global__ __launch_bounds__(BLOCK) void sampling_loss_finalize(
    const double* __restrict__ partials, float* __restrict__ out)
{
    double L = 0.0, M = 0.0;
    for (int i = threadIdx.x; i < GRID; i += BLOCK) {
        L += partials[2 * i + 0];
        M += partials[2 * i + 1];
    }
    for (int off = 32; off > 0; off >>= 1) {
        L += __shfl_down(L, off);
        M += __shfl_down(M, off);
    }
    __shared__ double sL[BLOCK / 64];
    __shared__ double sM[BLOCK / 64];
    const int lane = threadIdx.x & 63;
    const int wave = threadIdx.x >> 6;
    if (lane == 0) { sL[wave] = L; sM[wave] = M; }
    __syncthreads();
    if (threadIdx.x == 0) {
        double tl = 0.0, tm = 0.0;
        for (int w = 0; w < BLOCK / 64; ++w) { tl += sL[w]; tm += sM[w]; }
        out[0] = (float)(tl / tm);
    }
}

extern "C" void kernel_launch(void* const* d_in, const int* in_sizes, int n_in,
                              void* d_out, int out_size, void* d_ws, size_t ws_size,
                              hipStream_t stream) {
    const float* translation = (const float*)d_in[0];
    const float* yaw         = (const float*)d_in[1];
    const float* pitch       = (const float*)d_in[2];
    const float* roll        = (const float*)d_in[3];
    const float* xyz         = (const float*)d_in[4];
    const float* rgb         = (const float*)d_in[5];
    const float* img         = (const float*)d_in[6];
    const float* imgw        = (const float*)d_in[7];
    const float* pcdw        = (const float*)d_in[8];

    const int N = in_sizes[8];  // pcd_weight has one element per point

    double* partials = (double*)d_ws;  // GRID*2 doubles = 32 KiB
    float* out = (float*)d_out;

    sampling_loss_partial<<<GRID, BLOCK, 0, stream>>>(
        translation, yaw, pitch, roll, xyz, rgb, img, imgw, pcdw, partials, N);
    sampling_loss_finalize<<<1, BLOCK, 0, stream>>>(partials, out);
}

// Round 2
// 59.826 us; speedup vs baseline: 1.7293x; 1.7293x over previous
//
#include <hip/hip_runtime.h>
#include <hip/hip_fp16.h>
#include <math.h>

#define PI_F 3.14159265358979323846f

constexpr int IMG_H = 1024;
constexpr int IMG_W = 2048;
constexpr int BLOCK = 256;
constexpr int GRID  = 2048;

constexpr size_t PARTIALS_BYTES = 64 * 1024;                       // 2048*2 doubles fits in 32K; pad to 64K
constexpr size_t TEX_BYTES = (size_t)IMG_H * IMG_W * 8;            // ushort4 per texel

// ---------------- repack: (img f32x3, imgw f32x1) -> fp16x4 texel ----------------
__global__ __launch_bounds__(BLOCK) void repack_tex(
    const float* __restrict__ img,   // (H,W,3)
    const float* __restrict__ imgw,  // (H,W,1)
    ushort4* __restrict__ tex)       // (H*W)
{
    int idx = blockIdx.x * BLOCK + threadIdx.x;
    const int total = IMG_H * IMG_W;
    if (idx < total) {
        float r = img[3 * idx + 0];
        float g = img[3 * idx + 1];
        float b = img[3 * idx + 2];
        float w = imgw[idx];
        ushort4 t;
        t.x = __half_as_ushort(__float2half(r));
        t.y = __half_as_ushort(__float2half(g));
        t.z = __half_as_ushort(__float2half(b));
        t.w = __half_as_ushort(__float2half(w));
        tex[idx] = t;
    }
}

// ---------------- stage 1: fused loss with packed fp16 texture ----------------
__global__ __launch_bounds__(BLOCK) void sampling_loss_packed(
    const float* __restrict__ translation,
    const float* __restrict__ yaw,
    const float* __restrict__ pitch,
    const float* __restrict__ roll,
    const float* __restrict__ xyz,
    const float* __restrict__ rgb,
    const ushort4* __restrict__ tex,
    const float* __restrict__ pcdw,
    double* __restrict__ partials,
    int N)
{
    const float cyw = cosf(yaw[0]),   syw = sinf(yaw[0]);
    const float cpw = cosf(pitch[0]), spw = sinf(pitch[0]);
    const float crw = cosf(roll[0]),  srw = sinf(roll[0]);

    const float R00 = cyw * cpw;
    const float R01 = -syw * crw + cyw * spw * srw;
    const float R02 =  syw * srw + cyw * spw * crw;
    const float R10 =  syw * cpw;
    const float R11 =  cyw * crw + syw * spw * srw;
    const float R12 = -cyw * srw + syw * spw * crw;
    const float R20 = -spw;
    const float R21 =  cpw * srw;
    const float R22 =  cpw * crw;

    const float tx = translation[0], ty = translation[1], tz = translation[2];

    double acc_loss = 0.0;
    double acc_mask = 0.0;

    for (int i = blockIdx.x * BLOCK + threadIdx.x; i < N; i += GRID * BLOCK) {
        // streaming inputs: zero reuse -> non-temporal (keep L2 for the texture)
        const float xr = __builtin_nontemporal_load(&xyz[3 * i + 0]);
        const float yr = __builtin_nontemporal_load(&xyz[3 * i + 1]);
        const float zr = __builtin_nontemporal_load(&xyz[3 * i + 2]);
        const float cr0 = __builtin_nontemporal_load(&rgb[3 * i + 0]);
        const float cg0 = __builtin_nontemporal_load(&rgb[3 * i + 1]);
        const float cb0 = __builtin_nontemporal_load(&rgb[3 * i + 2]);
        const float pw  = __builtin_nontemporal_load(&pcdw[i]);

        const float px = xr - tx;
        const float py = yr - ty;
        const float pz = zr - tz;

        const float nx = R00 * px + R01 * py + R02 * pz;
        const float ny = R10 * px + R11 * py + R12 * pz;
        const float nz = R20 * px + R21 * py + R22 * pz;

        const float phi   = atan2f(ny, nx) + PI_F;
        const float theta = atan2f(sqrtf(nx * nx + ny * ny), nz);
        const float cx = 2.0f * (1.0f - phi / (2.0f * PI_F)) - 1.0f;
        const float cyv = 2.0f * (theta / PI_F) - 1.0f;

        float fx = (cx + 1.0f) * 0.5f * (float)IMG_W - 0.5f;
        float fy = (cyv + 1.0f) * 0.5f * (float)IMG_H - 0.5f;
        fx = fminf(fmaxf(fx, 0.0f), (float)(IMG_W - 1));
        fy = fminf(fmaxf(fy, 0.0f), (float)(IMG_H - 1));

        const float x0f = floorf(fx), y0f = floorf(fy);
        const float wx = fx - x0f,    wy = fy - y0f;
        const int x0 = (int)x0f, y0 = (int)y0f;
        const int x1 = min(x0 + 1, IMG_W - 1);
        const int y1 = min(y0 + 1, IMG_H - 1);

        const float w00 = (1.0f - wx) * (1.0f - wy);
        const float w01 = wx * (1.0f - wy);
        const float w10 = (1.0f - wx) * wy;
        const float w11 = wx * wy;

        const ushort4 t00 = tex[y0 * IMG_W + x0];
        const ushort4 t01 = tex[y0 * IMG_W + x1];
        const ushort4 t10 = tex[y1 * IMG_W + x0];
        const ushort4 t11 = tex[y1 * IMG_W + x1];

        const float s0 = w00 * __half2float(__ushort_as_half(t00.x))
                       + w01 * __half2float(__ushort_as_half(t01.x))
                       + w10 * __half2float(__ushort_as_half(t10.x))
                       + w11 * __half2float(__ushort_as_half(t11.x));
        const float s1 = w00 * __half2float(__ushort_as_half(t00.y))
                       + w01 * __half2float(__ushort_as_half(t01.y))
                       + w10 * __half2float(__ushort_as_half(t10.y))
                       + w11 * __half2float(__ushort_as_half(t11.y));
        const float s2 = w00 * __half2float(__ushort_as_half(t00.z))
                       + w01 * __half2float(__ushort_as_half(t01.z))
                       + w10 * __half2float(__ushort_as_half(t10.z))
                       + w11 * __half2float(__ushort_as_half(t11.z));
        const float wimg = w00 * __half2float(__ushort_as_half(t00.w))
                         + w01 * __half2float(__ushort_as_half(t01.w))
                         + w10 * __half2float(__ushort_as_half(t10.w))
                         + w11 * __half2float(__ushort_as_half(t11.w));

        const float dr = s0 - cr0;
        const float dg = s1 - cg0;
        const float db = s2 - cb0;
        const float raw = sqrtf(dr * dr + dg * dg + db * db);

        const bool mask = !((s0 == 0.0f) && (s1 == 0.0f) && (s2 == 0.0f));

        const float li = 0.5f * (wimg + pw) * raw;
        if (mask) {
            acc_loss += (double)li;
            acc_mask += 1.0;
        }
    }

    for (int off = 32; off > 0; off >>= 1) {
        acc_loss += __shfl_down(acc_loss, off);
        acc_mask += __shfl_down(acc_mask, off);
    }

    __shared__ double sL[BLOCK / 64];
    __shared__ double sM[BLOCK / 64];
    const int lane = threadIdx.x & 63;
    const int wave = threadIdx.x >> 6;
    if (lane == 0) { sL[wave] = acc_loss; sM[wave] = acc_mask; }
    __syncthreads();
    if (threadIdx.x == 0) {
        double L = 0.0, M = 0.0;
        for (int w = 0; w < BLOCK / 64; ++w) { L += sL[w]; M += sM[w]; }
        partials[2 * blockIdx.x + 0] = L;
        partials[2 * blockIdx.x + 1] = M;
    }
}

// ---------------- fallback stage 1 (f32 gathers, no scratch texture) ----------------
__global__ __launch_bounds__(BLOCK) void sampling_loss_partial(
    const float* __restrict__ translation,
    const float* __restrict__ yaw,
    const float* __restrict__ pitch,
    const float* __restrict__ roll,
    const float* __restrict__ xyz,
    const float* __restrict__ rgb,
    const float* __restrict__ img,
    const float* __restrict__ imgw,
    const float* __restrict__ pcdw,
    double* __restrict__ partials,
    int N)
{
    const float cyw = cosf(yaw[0]),   syw = sinf(yaw[0]);
    const float cpw = cosf(pitch[0]), spw = sinf(pitch[0]);
    const float crw = cosf(roll[0]),  srw = sinf(roll[0]);

    const float R00 = cyw * cpw;
    const float R01 = -syw * crw + cyw * spw * srw;
    const float R02 =  syw * srw + cyw * spw * crw;
    const float R10 =  syw * cpw;
    const float R11 =  cyw * crw + syw * spw * srw;
    const float R12 = -cyw * srw + syw * spw * crw;
    const float R20 = -spw;
    const float R21 =  cpw * srw;
    const float R22 =  cpw * crw;

    const float tx = translation[0], ty = translation[1], tz = translation[2];

    double acc_loss = 0.0;
    double acc_mask = 0.0;

    for (int i = blockIdx.x * BLOCK + threadIdx.x; i < N; i += GRID * BLOCK) {
        const float px = xyz[3 * i + 0] - tx;
        const float py = xyz[3 * i + 1] - ty;
        const float pz = xyz[3 * i + 2] - tz;

        const float nx = R00 * px + R01 * py + R02 * pz;
        const float ny = R10 * px + R11 * py + R12 * pz;
        const float nz = R20 * px + R21 * py + R22 * pz;

        const float phi   = atan2f(ny, nx) + PI_F;
        const float theta = atan2f(sqrtf(nx * nx + ny * ny), nz);
        const float cx = 2.0f * (1.0f - phi / (2.0f * PI_F)) - 1.0f;
        const float cyv = 2.0f * (theta / PI_F) - 1.0f;

        float fx = (cx + 1.0f) * 0.5f * (float)IMG_W - 0.5f;
        float fy = (cyv + 1.0f) * 0.5f * (float)IMG_H - 0.5f;
        fx = fminf(fmaxf(fx, 0.0f), (float)(IMG_W - 1));
        fy = fminf(fmaxf(fy, 0.0f), (float)(IMG_H - 1));

        const float x0f = floorf(fx), y0f = floorf(fy);
        const float wx = fx - x0f,    wy = fy - y0f;
        const int x0 = (int)x0f, y0 = (int)y0f;
        const int x1 = min(x0 + 1, IMG_W - 1);
        const int y1 = min(y0 + 1, IMG_H - 1);

        const float w00 = (1.0f - wx) * (1.0f - wy);
        const float w01 = wx * (1.0f - wy);
        const float w10 = (1.0f - wx) * wy;
        const float w11 = wx * wy;

        const float* p00 = img + (size_t)(y0 * IMG_W + x0) * 3;
        const float* p01 = img + (size_t)(y0 * IMG_W + x1) * 3;
        const float* p10 = img + (size_t)(y1 * IMG_W + x0) * 3;
        const float* p11 = img + (size_t)(y1 * IMG_W + x1) * 3;

        const float s0 = w00 * p00[0] + w01 * p01[0] + w10 * p10[0] + w11 * p11[0];
        const float s1 = w00 * p00[1] + w01 * p01[1] + w10 * p10[1] + w11 * p11[1];
        const float s2 = w00 * p00[2] + w01 * p01[2] + w10 * p10[2] + w11 * p11[2];

        const float wimg = w00 * imgw[y0 * IMG_W + x0] + w01 * imgw[y0 * IMG_W + x1]
                         + w10 * imgw[y1 * IMG_W + x0] + w11 * imgw[y1 * IMG_W + x1];

        const float dr = s0 - rgb[3 * i + 0];
        const float dg = s1 - rgb[3 * i + 1];
        const float db = s2 - rgb[3 * i + 2];
        const float raw = sqrtf(dr * dr + dg * dg + db * db);

        const bool mask = !((s0 == 0.0f) && (s1 == 0.0f) && (s2 == 0.0f));

        const float li = 0.5f * (wimg + pcdw[i]) * raw;
        if (mask) {
            acc_loss += (double)li;
            acc_mask += 1.0;
        }
    }

    for (int off = 32; off > 0; off >>= 1) {
        acc_loss += __shfl_down(acc_loss, off);
        acc_mask += __shfl_down(acc_mask, off);
    }

    __shared__ double sL[BLOCK / 64];
    __shared__ double sM[BLOCK / 64];
    const int lane = threadIdx.x & 63;
    const int wave = threadIdx.x >> 6;
    if (lane == 0) { sL[wave] = acc_loss; sM[wave] = acc_mask; }
    __syncthreads();
    if (threadIdx.x == 0) {
        double L = 0.0, M = 0.0;
        for (int w = 0; w < BLOCK / 64; ++w) { L += sL[w]; M += sM[w]; }
        partials[2 * blockIdx.x + 0] = L;
        partials[2 * blockIdx.x + 1] = M;
    }
}

// ---------------- stage 2: deterministic finalize ----------------
__global__ __launch_bounds__(BLOCK) void sampling_loss_finalize(
    const double* __restrict__ partials, float* __restrict__ out)
{
    double L = 0.0, M = 0.0;
    for (int i = threadIdx.x; i < GRID; i += BLOCK) {
        L += partials[2 * i + 0];
        M += partials[2 * i + 1];
    }
    for (int off = 32; off > 0; off >>= 1) {
        L += __shfl_down(L, off);
        M += __shfl_down(M, off);
    }
    __shared__ double sL[BLOCK / 64];
    __shared__ double sM[BLOCK / 64];
    const int lane = threadIdx.x & 63;
    const int wave = threadIdx.x >> 6;
    if (lane == 0) { sL[wave] = L; sM[wave] = M; }
    __syncthreads();
    if (threadIdx.x == 0) {
        double tl = 0.0, tm = 0.0;
        for (int w = 0; w < BLOCK / 64; ++w) { tl += sL[w]; tm += sM[w]; }
        out[0] = (float)(tl / tm);
    }
}

extern "C" void kernel_launch(void* const* d_in, const int* in_sizes, int n_in,
                              void* d_out, int out_size, void* d_ws, size_t ws_size,
                              hipStream_t stream) {
    const float* translation = (const float*)d_in[0];
    const float* yaw         = (const float*)d_in[1];
    const float* pitch       = (const float*)d_in[2];
    const float* roll        = (const float*)d_in[3];
    const float* xyz         = (const float*)d_in[4];
    const float* rgb         = (const float*)d_in[5];
    const float* img         = (const float*)d_in[6];
    const float* imgw        = (const float*)d_in[7];
    const float* pcdw        = (const float*)d_in[8];

    const int N = in_sizes[8];

    double* partials = (double*)d_ws;
    float* out = (float*)d_out;

    if (ws_size >= PARTIALS_BYTES + TEX_BYTES) {
        ushort4* tex = (ushort4*)((char*)d_ws + PARTIALS_BYTES);
        const int total = IMG_H * IMG_W;
        repack_tex<<<(total + BLOCK - 1) / BLOCK, BLOCK, 0, stream>>>(img, imgw, tex);
        sampling_loss_packed<<<GRID, BLOCK, 0, stream>>>(
            translation, yaw, pitch, roll, xyz, rgb, tex, pcdw, partials, N);
    } else {
        sampling_loss_partial<<<GRID, BLOCK, 0, stream>>>(
            translation, yaw, pitch, roll, xyz, rgb, img, imgw, pcdw, partials, N);
    }
    sampling_loss_finalize<<<1, BLOCK, 0, stream>>>(partials, out);
}